// Round 13
// baseline (277.537 us; speedup 1.0000x reference)
//
#include <hip/hip_runtime.h>
#include <stdint.h>

// Problem dims (fixed by reference)
#define B_ 8
#define T_ 1024
#define E_ 1024
#define H_ 16
#define S_ 64

typedef __attribute__((ext_vector_type(8))) short bf16x8;   // 8 bf16 in 4 VGPRs
typedef __attribute__((ext_vector_type(4))) short bf16x4;   // 4 bf16 in 2 VGPRs
typedef __attribute__((ext_vector_type(4))) float f32x4;

// Call amdgcn builtins DIRECTLY — __has_builtin fails on hipcc host pass (r4/r5).
__device__ __forceinline__ f32x4 mfma_pv(bf16x4 a, bf16x4 b, f32x4 c) {
  return __builtin_amdgcn_mfma_f32_16x16x16bf16_1k(a, b, c, 0, 0, 0);
}

// raw v_exp_f32 — no OCML guard (masked logits are -1e30 -> exp2 = 0 exactly)
__device__ __forceinline__ float e2(float x) { return __builtin_amdgcn_exp2f(x); }

__device__ __forceinline__ ushort f2bf(float f) {
  union { float f; uint32_t u; } v; v.f = f;
  uint32_t r = (v.u + 0x7FFFu + ((v.u >> 16) & 1u)) >> 16;  // RNE
  return (ushort)r;
}
__device__ __forceinline__ float bf2f(ushort u) {
  union { uint32_t u; float f; } v; v.u = ((uint32_t)u) << 16;
  return v.f;
}

// pack two f32 -> 2 bf16 in ONE instr (RNE).  S0 -> low half, S1 -> high.
__device__ __forceinline__ uint32_t cvtpk(float a, float b) {
  uint32_t r;
  asm("v_cvt_pk_bf16_f32 %0, %1, %2" : "=v"(r) : "v"(a), "v"(b));
  return r;
}
__device__ __forceinline__ bf16x4 pack4(const float* p) {
  union { uint32_t u[2]; bf16x4 v; } pu;
  pu.u[0] = cvtpk(p[0], p[1]);
  pu.u[1] = cvtpk(p[2], p[3]);
  return pu.v;
}

// async 16B global -> LDS (no VGPR roundtrip). LDS dest = uniform base + lane*16.
__device__ __forceinline__ void gload_lds16(const ushort* g, ushort* l) {
  __builtin_amdgcn_global_load_lds(
      (const __attribute__((address_space(1))) uint32_t*)g,
      (__attribute__((address_space(3))) uint32_t*)l, 16, 0, 0);
}

__device__ __forceinline__ bf16x8 load8(const void* p, size_t idx, bool isf32) {
  if (isf32) {
    const float* fp = (const float*)p + idx;
    f32x4 f0 = *(const f32x4*)(fp);
    f32x4 f1 = *(const f32x4*)(fp + 4);
    union { uint32_t u[4]; bf16x8 v; } r;
    r.u[0] = cvtpk(f0[0], f0[1]);
    r.u[1] = cvtpk(f0[2], f0[3]);
    r.u[2] = cvtpk(f1[0], f1[1]);
    r.u[3] = cvtpk(f1[2], f1[3]);
    return r.v;
  }
  return *(const bf16x8*)((const ushort*)p + idx);
}

// ---------------------------------------------------------------------------
// Inline dtype sniff: wave-uniform, no extra kernel launch.
// ---------------------------------------------------------------------------
__device__ __forceinline__ bool detect_f32_wave(const uint32_t* __restrict__ x) {
  const int lane = threadIdx.x & 63;
  int sane = 0;
  #pragma unroll
  for (int j = 0; j < 4; ++j) {
    uint32_t lo = x[lane * 4 + j] & 0xFFFFu;
    uint32_t e = (lo >> 7) & 0xFFu;
    sane += (e >= 96u && e <= 158u) ? 1 : 0;
  }
  #pragma unroll
  for (int off = 32; off >= 1; off >>= 1) sane += __shfl_xor(sane, off);
  return sane < 192;
}

// ---------------------------------------------------------------------------
// Kernel 0: pre-convert Wu (1024x1024), bu (1024) AND Wq/Wk/Wv (3x64x64) to
// bf16 once.  grid 519.  (r11 proved merging this into qkv costs ~25us.)
// ---------------------------------------------------------------------------
__global__ __launch_bounds__(256) void cvt_kernel(
    const void* __restrict__ x,
    const void* __restrict__ Wu, const void* __restrict__ bu,
    const void* __restrict__ Wq, const void* __restrict__ Wk,
    const void* __restrict__ Wv,
    ushort* __restrict__ wub, ushort* __restrict__ bub,
    ushort* __restrict__ wqkv) {
  const bool f32 = detect_f32_wave((const uint32_t*)x);
  if (blockIdx.x < 512) {
    size_t base = (size_t)blockIdx.x * 2048 + threadIdx.x * 8;
    *(bf16x8*)(wub + base) = load8(Wu, base, f32);
  } else if (blockIdx.x == 512) {
    if (threadIdx.x < 128) {
      size_t base = (size_t)threadIdx.x * 8;
      *(bf16x8*)(bub + base) = load8(bu, base, f32);
    }
  } else {
    const void* Ws[3] = {Wq, Wk, Wv};
    int idx = blockIdx.x - 513;           // 0..5
    int w = idx >> 1, half = idx & 1;
    size_t base = (size_t)half * 2048 + threadIdx.x * 8;
    *(bf16x8*)(wqkv + w * 4096 + base) = load8(Ws[w], base, f32);
  }
}

// ---------------------------------------------------------------------------
// Kernel 1: Q/K/V projection, blocked per (b,h,t-tile) — ROUND-4 EXACT.
// ---------------------------------------------------------------------------
#define QSCALE 0.045084220f   // 0.03125 * 1.44269504

__global__ __launch_bounds__(256) void qkv_kernel(
    const void* __restrict__ x, const ushort* __restrict__ wqkv,
    ushort* __restrict__ qb, ushort* __restrict__ kb, ushort* __restrict__ vb) {
  __shared__ ushort qs[64 * 72];
  __shared__ ushort ks[64 * 72];
  __shared__ ushort vs[64 * 72];   // transposed [s][t_local]
  const bool f32 = detect_f32_wave((const uint32_t*)x);
  const int tid = threadIdx.x;
  const int lane = tid & 63, wave = tid >> 6;
  const int m = lane & 15, quad = lane >> 4;
  const int tile = blockIdx.x & 15;
  const int h = (blockIdx.x >> 4) & 15;
  const int b = blockIdx.x >> 8;
  const int t0 = tile * 64;

  const size_t xrow = ((size_t)b * T_ + t0 + wave * 16 + m) * E_ + h * S_;
  bf16x8 a0 = load8(x, xrow + quad * 8, f32);
  bf16x8 a1 = load8(x, xrow + 32 + quad * 8, f32);

  #pragma unroll
  for (int w = 0; w < 3; ++w) {
    const float sc = (w == 0) ? QSCALE : 1.0f;
    ushort* dst = (w == 0) ? qs : (w == 1) ? ks : vs;
    #pragma unroll
    for (int nt = 0; nt < 4; ++nt) {
      const ushort* wrow = wqkv + w * 4096 + (nt * 16 + m) * S_;
      bf16x8 b0 = *(const bf16x8*)(wrow + quad * 8);
      bf16x8 b1 = *(const bf16x8*)(wrow + 32 + quad * 8);
      f32x4 acc = {0.f, 0.f, 0.f, 0.f};
      acc = __builtin_amdgcn_mfma_f32_16x16x32_bf16(a0, b0, acc, 0, 0, 0);
      acc = __builtin_amdgcn_mfma_f32_16x16x32_bf16(a1, b1, acc, 0, 0, 0);
      #pragma unroll
      for (int i = 0; i < 4; ++i) {
        int lr = wave * 16 + quad * 4 + i;  // local t row 0..63
        int o  = nt * 16 + m;               // output feature 0..63
        if (w == 2) {
          vs[o * 72 + lr] = f2bf(acc[i]);   // transposed stage
        } else {
          dst[lr * 72 + o] = f2bf(acc[i] * sc);
        }
      }
    }
  }

  __syncthreads();

  const int row = tid >> 2, ck = (tid & 3) * 16;
  const size_t qkbase = (((size_t)b * H_ + h) * T_ + t0 + row) * S_ + ck;
  *(bf16x8*)(qb + qkbase)     = *(const bf16x8*)(qs + row * 72 + ck);
  *(bf16x8*)(qb + qkbase + 8) = *(const bf16x8*)(qs + row * 72 + ck + 8);
  *(bf16x8*)(kb + qkbase)     = *(const bf16x8*)(ks + row * 72 + ck);
  *(bf16x8*)(kb + qkbase + 8) = *(const bf16x8*)(ks + row * 72 + ck + 8);
  const size_t vbase = (((size_t)b * H_ + h) * S_ + row) * T_ + t0 + ck;
  *(bf16x8*)(vb + vbase)      = *(const bf16x8*)(vs + row * 72 + ck);
  *(bf16x8*)(vb + vbase + 8)  = *(const bf16x8*)(vs + row * 72 + ck + 8);
}

// ---------------------------------------------------------------------------
// Kernel 2 (ROUND 13): r8 attn with V-in-REGISTER prefetch, done INLINE via
// macro (r5's mechanism without the function-boundary scratch bug).
//  - vlds deleted: LDS 32KB -> 16KB (residency cap 5 -> 10 blocks/CU).
//  - V(kt+1) loaded global->reg (16 x b64, L2-resident) at iteration start;
//    the per-kt __syncthreads (still required for the K double-buffer) is
//    the consume fence — same prefetch distance as the r4/r8 staging.
//  - 2-state vvA/vvB rotated by hand-unrolled kt loop; all static indices.
//  - K path byte-identical to r8.
// Spill tripwire: WRITE_SIZE must stay 16.4MB.
// ---------------------------------------------------------------------------
#define VLOAD(DST, KT)                                                        \
  _Pragma("unroll")                                                           \
  for (int v4 = 0; v4 < 4; ++v4) {                                            \
    _Pragma("unroll")                                                         \
    for (int nt = 0; nt < 4; ++nt) {                                          \
      DST[nt][v4] = *(const bf16x4*)(vbase + (size_t)(v4 * 16) * T_ +         \
                                     (KT) * 64 + nt * 16);                    \
    }                                                                         \
  }

#define ATTN_STEP(KT, VCUR, VNEXT, KREAD, KWRITE)                             \
  {                                                                           \
    const int kt_ = (KT);                                                     \
    const bool msk_ = (kt_ == qt) || ((kt_ + 1) * 64 > len);                  \
    if (kt_ < qt) {                                                           \
      const ushort* Kn_ = K + (size_t)(kt_ + 1) * 64 * S_;                    \
      _Pragma("unroll")                                                       \
      for (int p = 0; p < 2; ++p) {                                           \
        const int wrow = wave * 16 + p * 8;                                   \
        gload_lds16(Kn_ + (size_t)(wrow + sr) * S_ + ssw, (KWRITE) + wrow * 64); \
      }                                                                       \
      VLOAD(VNEXT, kt_ + 1)                                                   \
    }                                                                         \
    bf16x4 pf[4];                                                             \
    _Pragma("unroll")                                                         \
    for (int nt = 0; nt < 4; ++nt) {                                          \
      const ushort* krow = (KREAD) + (nt * 16 + m) * 64;                      \
      bf16x8 ak0 = *(const bf16x8*)(krow + ((8 * quad) ^ swzr));              \
      bf16x8 ak1 = *(const bf16x8*)(krow + ((32 + 8 * quad) ^ swzr));         \
      const int kl0 = kt_ * 64 + nt * 16 + quad * 4;                          \
      __builtin_amdgcn_s_setprio(1);                                          \
      f32x4 s4 = {0.f, 0.f, 0.f, 0.f};                                        \
      s4 = __builtin_amdgcn_mfma_f32_16x16x32_bf16(ak0, aq0, s4, 0, 0, 0);    \
      s4 = __builtin_amdgcn_mfma_f32_16x16x32_bf16(ak1, aq1, s4, 0, 0, 0);    \
      __builtin_amdgcn_s_setprio(0);                                          \
      float p4[4];                                                            \
      _Pragma("unroll")                                                       \
      for (int i = 0; i < 4; ++i) {                                           \
        float s = s4[i];                                                      \
        if (msk_) s = (kl0 + i <= qmin) ? s : -1e30f;                         \
        p4[i] = e2(s);                                                        \
      }                                                                       \
      pf[nt] = pack4(p4);                                                     \
    }                                                                         \
    __builtin_amdgcn_s_setprio(1);                                            \
    _Pragma("unroll")                                                         \
    for (int nt = 0; nt < 4; ++nt) {                                          \
      Lacc = mfma_pv(pf[nt], ones, Lacc);                                     \
      _Pragma("unroll")                                                       \
      for (int v4 = 0; v4 < 4; ++v4)                                          \
        o[v4] = mfma_pv(pf[nt], VCUR[nt][v4], o[v4]);                         \
    }                                                                         \
    __builtin_amdgcn_s_setprio(0);                                            \
    if (kt_ < qt) __syncthreads();                                            \
  }

__global__ __launch_bounds__(256) void attn_kernel(
    const ushort* __restrict__ qb, const ushort* __restrict__ kb,
    const ushort* __restrict__ vb, const int* __restrict__ lengths,
    ushort* __restrict__ ao) {
  __shared__ ushort klds[2][64 * 64];

  const int tid = threadIdx.x;
  const int lane = tid & 63, wave = tid >> 6;
  const int m = lane & 15, quad = lane >> 4;
  const int ord = blockIdx.x >> 7;         // 0..15, dispatch order
  const int bh = blockIdx.x & 127;
  const int b  = bh >> 4, h = bh & 15;
  const int qt = 15 - ord;                 // longest q-tiles first (LPT)
  const int len = lengths[b];

  const size_t head_off = ((size_t)b * H_ + h) * (size_t)T_ * S_;
  const ushort* Q  = qb + head_off;
  const ushort* K  = kb + head_off;
  const ushort* Vt = vb + head_off;         // [s][t], row stride T_

  const int sr  = lane >> 3;                     // row-within-8 (0..7)
  const int ssw = 8 * ((lane & 7) ^ sr);         // swizzled source col (ushorts)
  const int swzr = 8 * (m & 7);                  // read-side swizzle term

  const int qw = qt * 64 + wave * 16;
  bf16x8 aq0 = *(const bf16x8*)(Q + (size_t)(qw + m) * S_ + quad * 8);
  bf16x8 aq1 = *(const bf16x8*)(Q + (size_t)(qw + m) * S_ + 32 + quad * 8);

  const int qmin = min(qw + m, len - 1);

  // per-thread V base: row m (+v4*16), col quad*4 (+nt*16 +kt*64)
  const ushort* vbase = Vt + (size_t)m * T_ + quad * 4;

  f32x4 o[4], Lacc;
  #pragma unroll
  for (int i = 0; i < 4; ++i) o[i] = (f32x4){0.f, 0.f, 0.f, 0.f};
  Lacc = (f32x4){0.f, 0.f, 0.f, 0.f};

  bf16x4 ones;
  #pragma unroll
  for (int i = 0; i < 4; ++i) ones[i] = (short)0x3F80;  // bf16 1.0

  bf16x4 vvA[4][4], vvB[4][4];

  // prologue: stage K(0) (async) + V(0) straight to registers
  #pragma unroll
  for (int p = 0; p < 2; ++p) {
    const int wrow = wave * 16 + p * 8;
    gload_lds16(K + (size_t)(wrow + sr) * S_ + ssw, &klds[0][wrow * 64]);
  }
  VLOAD(vvA, 0)
  __syncthreads();

  // hand-unrolled by 2: static vvA/vvB + static K buffer parity (rule #20;
  // macro expansion, not a function — r5's scratch bug does not apply)
  for (int kt = 0; kt <= qt; kt += 2) {
    ATTN_STEP(kt, vvA, vvB, klds[0], klds[1])
    if (kt + 1 <= qt) {
      ATTN_STEP(kt + 1, vvB, vvA, klds[1], klds[0])
    }
  }

  // epilogue: L already in row-domain (Lacc[i] <-> q = qw + quad*4 + i)
  #pragma unroll
  for (int i = 0; i < 4; ++i) {
    float il = (Lacc[i] > 0.f) ? 1.0f / Lacc[i] : 0.f;
    size_t base = ((size_t)b * T_ + qw + quad * 4 + i) * E_ + h * 64;
    #pragma unroll
    for (int v4 = 0; v4 < 4; ++v4)
      ao[base + v4 * 16 + m] = f2bf(o[v4][i] * il);
  }
}

// ---------------------------------------------------------------------------
// Kernel 3: Y = att @ Wu^T + bu — ROUND-7 EXACT.
// ---------------------------------------------------------------------------
__global__ __launch_bounds__(256) void proj_kernel(
    const ushort* __restrict__ A, const ushort* __restrict__ Wu,
    const ushort* __restrict__ bu, float* __restrict__ Y) {
  __shared__ ushort As[128 * 72];
  __shared__ ushort Bs[128 * 72];
  const int tid = threadIdx.x;
  const int lane = tid & 63, wave = tid >> 6;
  const int m = lane & 15, quad = lane >> 4;
  const int m0 = blockIdx.x * 128, n0 = blockIdx.y * 128;
  const int wm = (wave & 1) * 64, wn = (wave >> 1) * 64;

  f32x4 acc[4][4];
  #pragma unroll
  for (int i = 0; i < 4; ++i)
    #pragma unroll
    for (int j = 0; j < 4; ++j) acc[i][j] = (f32x4){0.f, 0.f, 0.f, 0.f};

  bf16x8 pa[4], pb[4];
  #pragma unroll
  for (int p = 0; p < 4; ++p) {
    int c = tid + p * 256;
    int row = c >> 3, col = (c & 7) * 8;
    pa[p] = *(const bf16x8*)(A + (size_t)(m0 + row) * E_ + col);
    pb[p] = *(const bf16x8*)(Wu + (size_t)(n0 + row) * E_ + col);
  }

  for (int k0 = 0; k0 < E_; k0 += 64) {
    __syncthreads();
    #pragma unroll
    for (int p = 0; p < 4; ++p) {
      int c = tid + p * 256;
      int row = c >> 3, col = (c & 7) * 8;
      *(bf16x8*)(As + row * 72 + col) = pa[p];
      *(bf16x8*)(Bs + row * 72 + col) = pb[p];
    }
    __syncthreads();

    if (k0 + 64 < E_) {
      #pragma unroll
      for (int p = 0; p < 4; ++p) {
        int c = tid + p * 256;
        int row = c >> 3, col = (c & 7) * 8;
        pa[p] = *(const bf16x8*)(A + (size_t)(m0 + row) * E_ + k0 + 64 + col);
        pb[p] = *(const bf16x8*)(Wu + (size_t)(n0 + row) * E_ + k0 + 64 + col);
      }
    }

    #pragma unroll
    for (int kk = 0; kk < 64; kk += 32) {
      bf16x8 af[4], bfrag[4];
      #pragma unroll
      for (int i = 0; i < 4; ++i)
        af[i] = *(const bf16x8*)(As + (wm + i * 16 + m) * 72 + kk + quad * 8);
      #pragma unroll
      for (int j = 0; j < 4; ++j)
        bfrag[j] = *(const bf16x8*)(Bs + (wn + j * 16 + m) * 72 + kk + quad * 8);
      #pragma unroll
      for (int i = 0; i < 4; ++i)
        #pragma unroll
        for (int j = 0; j < 4; ++j)
          acc[i][j] = __builtin_amdgcn_mfma_f32_16x16x32_bf16(af[i], bfrag[j], acc[i][j], 0, 0, 0);
    }
  }

  #pragma unroll
  for (int j = 0; j < 4; ++j) {
    float bias = bf2f(bu[n0 + wn + j * 16 + m]);
    #pragma unroll
    for (int i = 0; i < 4; ++i) {
      #pragma unroll
      for (int r = 0; r < 4; ++r) {
        int grow = m0 + wm + i * 16 + quad * 4 + r;
        int gcol = n0 + wn + j * 16 + m;
        Y[(size_t)grow * E_ + gcol] = acc[i][j][r] + bias;
      }
    }
  }
}

// ---------------------------------------------------------------------------
extern "C" void kernel_launch(void* const* d_in, const int* in_sizes, int n_in,
                              void* d_out, int out_size, void* d_ws, size_t ws_size,
                              hipStream_t stream) {
  // setup_inputs order: x, lengths, Wk, Wq, Wv, Wu, bu
  const void* x  = d_in[0];
  const int* lengths = (const int*)d_in[1];
  const void* Wk = d_in[2];
  const void* Wq = d_in[3];
  const void* Wv = d_in[4];
  const void* Wu = d_in[5];
  const void* bu = d_in[6];
  float* out = (float*)d_out;

  // ws: Q,K [b][h][t][s], V^T [b][h][s][t], att_out [b][t][e], Wu/bu/Wqkv bf16
  const size_t hsz = (size_t)B_ * H_ * T_ * S_;
  ushort* qb   = (ushort*)d_ws;
  ushort* kb   = qb + hsz;
  ushort* vb   = kb + hsz;
  ushort* ao   = vb + hsz;
  ushort* wub  = ao + hsz;
  ushort* bub  = wub + (size_t)E_ * E_;
  ushort* wqkv = bub + E_;               // 3 x 64 x 64 bf16

  cvt_kernel<<<dim3(519), dim3(256), 0, stream>>>(x, Wu, bu, Wq, Wk, Wv, wub, bub, wqkv);
  qkv_kernel<<<dim3(B_ * H_ * (T_ / 64)), dim3(256), 0, stream>>>(x, wqkv, qb, kb, vb);
  attn_kernel<<<dim3(B_ * H_ * 16), dim3(256), 0, stream>>>(qb, kb, vb, lengths, ao);
  proj_kernel<<<dim3((B_ * T_) / 128, E_ / 128), dim3(256), 0, stream>>>(ao, wub, bub, out);
}

// Round 14
// 183.025 us; speedup vs baseline: 1.5164x; 1.5164x over previous
//
#include <hip/hip_runtime.h>
#include <stdint.h>

// Problem dims (fixed by reference)
#define B_ 8
#define T_ 1024
#define E_ 1024
#define H_ 16
#define S_ 64

typedef __attribute__((ext_vector_type(8))) short bf16x8;   // 8 bf16 in 4 VGPRs
typedef __attribute__((ext_vector_type(4))) short bf16x4;   // 4 bf16 in 2 VGPRs
typedef __attribute__((ext_vector_type(4))) float f32x4;

// Call amdgcn builtins DIRECTLY — __has_builtin fails on hipcc host pass (r4/r5).
__device__ __forceinline__ f32x4 mfma_pv(bf16x4 a, bf16x4 b, f32x4 c) {
  return __builtin_amdgcn_mfma_f32_16x16x16bf16_1k(a, b, c, 0, 0, 0);
}

// raw v_exp_f32 — no OCML guard (masked logits are -1e30 -> exp2 = 0 exactly)
__device__ __forceinline__ float e2(float x) { return __builtin_amdgcn_exp2f(x); }

__device__ __forceinline__ ushort f2bf(float f) {
  union { float f; uint32_t u; } v; v.f = f;
  uint32_t r = (v.u + 0x7FFFu + ((v.u >> 16) & 1u)) >> 16;  // RNE
  return (ushort)r;
}
__device__ __forceinline__ float bf2f(ushort u) {
  union { uint32_t u; float f; } v; v.u = ((uint32_t)u) << 16;
  return v.f;
}

// pack two f32 -> 2 bf16 in ONE instr (RNE).  S0 -> low half, S1 -> high.
__device__ __forceinline__ uint32_t cvtpk(float a, float b) {
  uint32_t r;
  asm("v_cvt_pk_bf16_f32 %0, %1, %2" : "=v"(r) : "v"(a), "v"(b));
  return r;
}
__device__ __forceinline__ bf16x4 pack4(const float* p) {
  union { uint32_t u[2]; bf16x4 v; } pu;
  pu.u[0] = cvtpk(p[0], p[1]);
  pu.u[1] = cvtpk(p[2], p[3]);
  return pu.v;
}

// async 16B global -> LDS (no VGPR roundtrip). LDS dest = uniform base + lane*16.
__device__ __forceinline__ void gload_lds16(const ushort* g, ushort* l) {
  __builtin_amdgcn_global_load_lds(
      (const __attribute__((address_space(1))) uint32_t*)g,
      (__attribute__((address_space(3))) uint32_t*)l, 16, 0, 0);
}

__device__ __forceinline__ bf16x8 load8(const void* p, size_t idx, bool isf32) {
  if (isf32) {
    const float* fp = (const float*)p + idx;
    f32x4 f0 = *(const f32x4*)(fp);
    f32x4 f1 = *(const f32x4*)(fp + 4);
    union { uint32_t u[4]; bf16x8 v; } r;
    r.u[0] = cvtpk(f0[0], f0[1]);
    r.u[1] = cvtpk(f0[2], f0[3]);
    r.u[2] = cvtpk(f1[0], f1[1]);
    r.u[3] = cvtpk(f1[2], f1[3]);
    return r.v;
  }
  return *(const bf16x8*)((const ushort*)p + idx);
}

// ---------------------------------------------------------------------------
// Inline dtype sniff: wave-uniform, no extra kernel launch.
// ---------------------------------------------------------------------------
__device__ __forceinline__ bool detect_f32_wave(const uint32_t* __restrict__ x) {
  const int lane = threadIdx.x & 63;
  int sane = 0;
  #pragma unroll
  for (int j = 0; j < 4; ++j) {
    uint32_t lo = x[lane * 4 + j] & 0xFFFFu;
    uint32_t e = (lo >> 7) & 0xFFu;
    sane += (e >= 96u && e <= 158u) ? 1 : 0;
  }
  #pragma unroll
  for (int off = 32; off >= 1; off >>= 1) sane += __shfl_xor(sane, off);
  return sane < 192;
}

// ---------------------------------------------------------------------------
// Kernel 0 (ROUND 14): pre-convert ONLY Wq/Wk/Wv (3x64x64, 6 blocks) — the
// part qkv needs immediately.  Wu/bu conversion moved into the attn grid
// (it's only consumed by proj, two kernels later) to overlap with attn's
// latency-bound execution instead of sitting serially in the chain.
// ---------------------------------------------------------------------------
__global__ __launch_bounds__(256) void cvt_kernel(
    const void* __restrict__ x,
    const void* __restrict__ Wq, const void* __restrict__ Wk,
    const void* __restrict__ Wv, ushort* __restrict__ wqkv) {
  const bool f32 = detect_f32_wave((const uint32_t*)x);
  const void* Ws[3] = {Wq, Wk, Wv};
  int w = blockIdx.x >> 1, half = blockIdx.x & 1;
  size_t base = (size_t)half * 2048 + threadIdx.x * 8;
  *(bf16x8*)(wqkv + w * 4096 + base) = load8(Ws[w], base, f32);
}

// ---------------------------------------------------------------------------
// Kernel 1: Q/K/V projection, blocked per (b,h,t-tile) — ROUND-4 EXACT.
// ---------------------------------------------------------------------------
#define QSCALE 0.045084220f   // 0.03125 * 1.44269504

__global__ __launch_bounds__(256) void qkv_kernel(
    const void* __restrict__ x, const ushort* __restrict__ wqkv,
    ushort* __restrict__ qb, ushort* __restrict__ kb, ushort* __restrict__ vb) {
  __shared__ ushort qs[64 * 72];
  __shared__ ushort ks[64 * 72];
  __shared__ ushort vs[64 * 72];   // transposed [s][t_local]
  const bool f32 = detect_f32_wave((const uint32_t*)x);
  const int tid = threadIdx.x;
  const int lane = tid & 63, wave = tid >> 6;
  const int m = lane & 15, quad = lane >> 4;
  const int tile = blockIdx.x & 15;
  const int h = (blockIdx.x >> 4) & 15;
  const int b = blockIdx.x >> 8;
  const int t0 = tile * 64;

  const size_t xrow = ((size_t)b * T_ + t0 + wave * 16 + m) * E_ + h * S_;
  bf16x8 a0 = load8(x, xrow + quad * 8, f32);
  bf16x8 a1 = load8(x, xrow + 32 + quad * 8, f32);

  #pragma unroll
  for (int w = 0; w < 3; ++w) {
    const float sc = (w == 0) ? QSCALE : 1.0f;
    ushort* dst = (w == 0) ? qs : (w == 1) ? ks : vs;
    #pragma unroll
    for (int nt = 0; nt < 4; ++nt) {
      const ushort* wrow = wqkv + w * 4096 + (nt * 16 + m) * S_;
      bf16x8 b0 = *(const bf16x8*)(wrow + quad * 8);
      bf16x8 b1 = *(const bf16x8*)(wrow + 32 + quad * 8);
      f32x4 acc = {0.f, 0.f, 0.f, 0.f};
      acc = __builtin_amdgcn_mfma_f32_16x16x32_bf16(a0, b0, acc, 0, 0, 0);
      acc = __builtin_amdgcn_mfma_f32_16x16x32_bf16(a1, b1, acc, 0, 0, 0);
      #pragma unroll
      for (int i = 0; i < 4; ++i) {
        int lr = wave * 16 + quad * 4 + i;  // local t row 0..63
        int o  = nt * 16 + m;               // output feature 0..63
        if (w == 2) {
          vs[o * 72 + lr] = f2bf(acc[i]);   // transposed stage
        } else {
          dst[lr * 72 + o] = f2bf(acc[i] * sc);
        }
      }
    }
  }

  __syncthreads();

  const int row = tid >> 2, ck = (tid & 3) * 16;
  const size_t qkbase = (((size_t)b * H_ + h) * T_ + t0 + row) * S_ + ck;
  *(bf16x8*)(qb + qkbase)     = *(const bf16x8*)(qs + row * 72 + ck);
  *(bf16x8*)(qb + qkbase + 8) = *(const bf16x8*)(qs + row * 72 + ck + 8);
  *(bf16x8*)(kb + qkbase)     = *(const bf16x8*)(ks + row * 72 + ck);
  *(bf16x8*)(kb + qkbase + 8) = *(const bf16x8*)(ks + row * 72 + ck + 8);
  const size_t vbase = (((size_t)b * H_ + h) * S_ + row) * T_ + t0 + ck;
  *(bf16x8*)(vb + vbase)      = *(const bf16x8*)(vs + row * 72 + ck);
  *(bf16x8*)(vb + vbase + 8)  = *(const bf16x8*)(vs + row * 72 + ck + 8);
}

// ---------------------------------------------------------------------------
// Kernel 2 (ROUND 14): blocks 0..512 convert Wu/bu (one-shot, ~2us, overlaps
// with attn's latency-bound execution — pipes are <40% busy).  Blocks
// 513..2560 are the ROUND-8-EXACT attention (proven 44.4us): ONE q-tile per
// block, K+V double-buffered LDS via source-swizzled gload_lds, V batch-read
// to registers under QK/exp, pure-register PV, L via ones-MFMA, LPT order.
// ---------------------------------------------------------------------------
__global__ __launch_bounds__(256, 3) void attn_kernel(
    const ushort* __restrict__ qb, const ushort* __restrict__ kb,
    const ushort* __restrict__ vb, const int* __restrict__ lengths,
    ushort* __restrict__ ao,
    const void* __restrict__ Wu, const void* __restrict__ bu,
    ushort* __restrict__ wub, ushort* __restrict__ bub) {
  __shared__ ushort klds[2][64 * 64];
  __shared__ ushort vlds[2][64 * 64];

  if (blockIdx.x < 513) {
    // concurrent Wu/bu bf16 conversion (consumed only by proj, later)
    const bool f32c = detect_f32_wave((const uint32_t*)qb);  // qb holds bf16 Q -> never f32-shaped; use Wu sniff below
    (void)f32c;
    const bool f32 = detect_f32_wave((const uint32_t*)Wu) ||
                     (sizeof(float) == 4 && false);
    // NOTE: sniff on Wu itself — same heuristic (bf16-in-low-half check);
    // Wu dtype matches x dtype in this harness.
    if (blockIdx.x < 512) {
      size_t base = (size_t)blockIdx.x * 2048 + threadIdx.x * 8;
      *(bf16x8*)(wub + base) = load8(Wu, base, f32);
    } else if (threadIdx.x < 128) {
      size_t base = (size_t)threadIdx.x * 8;
      *(bf16x8*)(bub + base) = load8(bu, base, f32);
    }
    return;
  }

  const int tid = threadIdx.x;
  const int lane = tid & 63, wave = tid >> 6;
  const int m = lane & 15, quad = lane >> 4;
  const int abid = blockIdx.x - 513;       // 0..2047
  const int ord = abid >> 7;               // 0..15, dispatch order
  const int bh = abid & 127;
  const int b  = bh >> 4, h = bh & 15;
  const int qt = 15 - ord;                 // longest q-tiles first (LPT)
  const int len = lengths[b];

  const size_t head_off = ((size_t)b * H_ + h) * (size_t)T_ * S_;
  const ushort* Q  = qb + head_off;
  const ushort* K  = kb + head_off;
  const ushort* Vt = vb + head_off;         // [s][t], row stride T_

  const int sr  = lane >> 3;                     // row-within-8 (0..7)
  const int ssw = 8 * ((lane & 7) ^ sr);         // swizzled source col (ushorts)
  const int swzr = 8 * (m & 7);                  // read-side swizzle term

  const int qw = qt * 64 + wave * 16;
  bf16x8 aq0 = *(const bf16x8*)(Q + (size_t)(qw + m) * S_ + quad * 8);
  bf16x8 aq1 = *(const bf16x8*)(Q + (size_t)(qw + m) * S_ + 32 + quad * 8);

  const int qmin = min(qw + m, len - 1);

  f32x4 o[4], Lacc;
  #pragma unroll
  for (int i = 0; i < 4; ++i) o[i] = (f32x4){0.f, 0.f, 0.f, 0.f};
  Lacc = (f32x4){0.f, 0.f, 0.f, 0.f};

  bf16x4 ones;
  #pragma unroll
  for (int i = 0; i < 4; ++i) ones[i] = (short)0x3F80;  // bf16 1.0

  // prologue: stage K[0] and V[0] (async, 4 gload_lds per wave)
  #pragma unroll
  for (int p = 0; p < 2; ++p) {
    const int wrow = wave * 16 + p * 8;
    gload_lds16(K  + (size_t)(wrow + sr) * S_ + ssw, &klds[0][wrow * 64]);
    gload_lds16(Vt + (size_t)(wrow + sr) * T_ + ssw, &vlds[0][wrow * 64]);
  }
  __syncthreads();

  for (int kt = 0; kt <= qt; ++kt) {
    const bool msk = (kt == qt) || ((kt + 1) * 64 > len);

    // async stage next K+V tiles into the other LDS buffers
    if (kt < qt) {
      const ushort* Kn = K + (size_t)(kt + 1) * 64 * S_;
      #pragma unroll
      for (int p = 0; p < 2; ++p) {
        const int wrow = wave * 16 + p * 8;
        gload_lds16(Kn + (size_t)(wrow + sr) * S_ + ssw,
                    &klds[(kt + 1) & 1][wrow * 64]);
        gload_lds16(Vt + (size_t)(wrow + sr) * T_ + (kt + 1) * 64 + ssw,
                    &vlds[(kt + 1) & 1][wrow * 64]);
      }
    }

    const ushort* kls = klds[kt & 1];
    const ushort* vls = vlds[kt & 1];

    // batch-read ALL current-tile V fragments into registers now; they land
    // under the QK/exp/pack phase (static indices).
    bf16x4 vv[4][4];
    #pragma unroll
    for (int nt = 0; nt < 4; ++nt) {
      #pragma unroll
      for (int v4 = 0; v4 < 4; ++v4) {
        vv[nt][v4] = *(const bf16x4*)(vls + (v4 * 16 + m) * 64 +
                                      8 * ((2 * nt + (quad >> 1)) ^ (m & 7)) +
                                      (quad & 1) * 4);
      }
    }

    bf16x4 pf[4];
    #pragma unroll
    for (int nt = 0; nt < 4; ++nt) {
      const ushort* krow = kls + (nt * 16 + m) * 64;
      bf16x8 ak0 = *(const bf16x8*)(krow + ((8 * quad) ^ swzr));
      bf16x8 ak1 = *(const bf16x8*)(krow + ((32 + 8 * quad) ^ swzr));
      const int kl0 = kt * 64 + nt * 16 + quad * 4;

      __builtin_amdgcn_s_setprio(1);
      f32x4 s4 = {0.f, 0.f, 0.f, 0.f};
      s4 = __builtin_amdgcn_mfma_f32_16x16x32_bf16(ak0, aq0, s4, 0, 0, 0);
      s4 = __builtin_amdgcn_mfma_f32_16x16x32_bf16(ak1, aq1, s4, 0, 0, 0);
      __builtin_amdgcn_s_setprio(0);

      float p4[4];
      #pragma unroll
      for (int i = 0; i < 4; ++i) {
        float s = s4[i];
        if (msk) s = (kl0 + i <= qmin) ? s : -1e30f;
        p4[i] = e2(s);                      // masked -> exp2(-1e30) = 0
      }
      pf[nt] = pack4(p4);
    }

    // PV + L accumulation — pure register operands
    __builtin_amdgcn_s_setprio(1);
    #pragma unroll
    for (int nt = 0; nt < 4; ++nt) {
      Lacc = mfma_pv(pf[nt], ones, Lacc);
      #pragma unroll
      for (int v4 = 0; v4 < 4; ++v4)
        o[v4] = mfma_pv(pf[nt], vv[nt][v4], o[v4]);
    }
    __builtin_amdgcn_s_setprio(0);

    if (kt < qt) __syncthreads();
  }

  // epilogue: L already in row-domain (Lacc[i] <-> q = qw + quad*4 + i)
  #pragma unroll
  for (int i = 0; i < 4; ++i) {
    float il = (Lacc[i] > 0.f) ? 1.0f / Lacc[i] : 0.f;
    size_t base = ((size_t)b * T_ + qw + quad * 4 + i) * E_ + h * 64;
    #pragma unroll
    for (int v4 = 0; v4 < 4; ++v4)
      ao[base + v4 * 16 + m] = f2bf(o[v4][i] * il);
  }
}

// ---------------------------------------------------------------------------
// Kernel 3: Y = att @ Wu^T + bu — ROUND-7 EXACT.
// ---------------------------------------------------------------------------
__global__ __launch_bounds__(256) void proj_kernel(
    const ushort* __restrict__ A, const ushort* __restrict__ Wu,
    const ushort* __restrict__ bu, float* __restrict__ Y) {
  __shared__ ushort As[128 * 72];
  __shared__ ushort Bs[128 * 72];
  const int tid = threadIdx.x;
  const int lane = tid & 63, wave = tid >> 6;
  const int m = lane & 15, quad = lane >> 4;
  const int m0 = blockIdx.x * 128, n0 = blockIdx.y * 128;
  const int wm = (wave & 1) * 64, wn = (wave >> 1) * 64;

  f32x4 acc[4][4];
  #pragma unroll
  for (int i = 0; i < 4; ++i)
    #pragma unroll
    for (int j = 0; j < 4; ++j) acc[i][j] = (f32x4){0.f, 0.f, 0.f, 0.f};

  bf16x8 pa[4], pb[4];
  #pragma unroll
  for (int p = 0; p < 4; ++p) {
    int c = tid + p * 256;
    int row = c >> 3, col = (c & 7) * 8;
    pa[p] = *(const bf16x8*)(A + (size_t)(m0 + row) * E_ + col);
    pb[p] = *(const bf16x8*)(Wu + (size_t)(n0 + row) * E_ + col);
  }

  for (int k0 = 0; k0 < E_; k0 += 64) {
    __syncthreads();
    #pragma unroll
    for (int p = 0; p < 4; ++p) {
      int c = tid + p * 256;
      int row = c >> 3, col = (c & 7) * 8;
      *(bf16x8*)(As + row * 72 + col) = pa[p];
      *(bf16x8*)(Bs + row * 72 + col) = pb[p];
    }
    __syncthreads();

    if (k0 + 64 < E_) {
      #pragma unroll
      for (int p = 0; p < 4; ++p) {
        int c = tid + p * 256;
        int row = c >> 3, col = (c & 7) * 8;
        pa[p] = *(const bf16x8*)(A + (size_t)(m0 + row) * E_ + k0 + 64 + col);
        pb[p] = *(const bf16x8*)(Wu + (size_t)(n0 + row) * E_ + k0 + 64 + col);
      }
    }

    #pragma unroll
    for (int kk = 0; kk < 64; kk += 32) {
      bf16x8 af[4], bfrag[4];
      #pragma unroll
      for (int i = 0; i < 4; ++i)
        af[i] = *(const bf16x8*)(As + (wm + i * 16 + m) * 72 + kk + quad * 8);
      #pragma unroll
      for (int j = 0; j < 4; ++j)
        bfrag[j] = *(const bf16x8*)(Bs + (wn + j * 16 + m) * 72 + kk + quad * 8);
      #pragma unroll
      for (int i = 0; i < 4; ++i)
        #pragma unroll
        for (int j = 0; j < 4; ++j)
          acc[i][j] = __builtin_amdgcn_mfma_f32_16x16x32_bf16(af[i], bfrag[j], acc[i][j], 0, 0, 0);
    }
  }

  #pragma unroll
  for (int j = 0; j < 4; ++j) {
    float bias = bf2f(bu[n0 + wn + j * 16 + m]);
    #pragma unroll
    for (int i = 0; i < 4; ++i) {
      #pragma unroll
      for (int r = 0; r < 4; ++r) {
        int grow = m0 + wm + i * 16 + quad * 4 + r;
        int gcol = n0 + wn + j * 16 + m;
        Y[(size_t)grow * E_ + gcol] = acc[i][j][r] + bias;
      }
    }
  }
}

// ---------------------------------------------------------------------------
extern "C" void kernel_launch(void* const* d_in, const int* in_sizes, int n_in,
                              void* d_out, int out_size, void* d_ws, size_t ws_size,
                              hipStream_t stream) {
  // setup_inputs order: x, lengths, Wk, Wq, Wv, Wu, bu
  const void* x  = d_in[0];
  const int* lengths = (const int*)d_in[1];
  const void* Wk = d_in[2];
  const void* Wq = d_in[3];
  const void* Wv = d_in[4];
  const void* Wu = d_in[5];
  const void* bu = d_in[6];
  float* out = (float*)d_out;

  // ws: Q,K [b][h][t][s], V^T [b][h][s][t], att_out [b][t][e], Wu/bu/Wqkv bf16
  const size_t hsz = (size_t)B_ * H_ * T_ * S_;
  ushort* qb   = (ushort*)d_ws;
  ushort* kb   = qb + hsz;
  ushort* vb   = kb + hsz;
  ushort* ao   = vb + hsz;
  ushort* wub  = ao + hsz;
  ushort* bub  = wub + (size_t)E_ * E_;
  ushort* wqkv = bub + E_;               // 3 x 64 x 64 bf16

  cvt_kernel<<<dim3(6), dim3(256), 0, stream>>>(x, Wq, Wk, Wv, wqkv);
  qkv_kernel<<<dim3(B_ * H_ * (T_ / 64)), dim3(256), 0, stream>>>(x, wqkv, qb, kb, vb);
  attn_kernel<<<dim3(513 + B_ * H_ * 16), dim3(256), 0, stream>>>(
      qb, kb, vb, lengths, ao, Wu, bu, wub, bub);
  proj_kernel<<<dim3((B_ * T_) / 128, E_ / 128), dim3(256), 0, stream>>>(ao, wub, bub, out);
}